// Round 14
// baseline (62.521 us; speedup 1.0000x reference)
//
#include <hip/hip_runtime.h>
#include <hip/hip_bf16.h>
#include <cstdint>

#define MAX_NORM (1.0f - 1e-5f)
#define LN2 0.69314718056f
// w-clamp equivalent of norm <= MAX_NORM: w_max = (1+MAX_NORM)/(1-MAX_NORM)
#define WMAX ((1.0f + MAX_NORM) / (1.0f - MAX_NORM))

typedef __attribute__((ext_vector_type(8))) short bf16x8;
typedef __attribute__((ext_vector_type(4))) float f32x4;

__device__ __forceinline__ unsigned short f2bf(float f) {
  union { float f; unsigned int u; } c; c.f = f;
  unsigned int r = c.u + 0x7fffu + ((c.u >> 16) & 1u);
  return (unsigned short)(r >> 16);
}

__device__ __forceinline__ void gld16(const unsigned short* g, unsigned short* l) {
  __builtin_amdgcn_global_load_lds(
      (const __attribute__((address_space(1))) unsigned int*)g,
      (__attribute__((address_space(3))) unsigned int*)l, 16, 0, 0);
}

// Fused prep: one wave per row, rows [0,M) are x, rows [M,M+N) are protos.
// x:      bf16-cast; x2 = ||x||^2; fx = 2/(1-x2)
// protos: expmap0+project -> bf16; gy = 1/(1-y2); hy = gy*y2; es2 = -exp(ls)*ln2
__global__ void prep_all(const float* __restrict__ x, const float* __restrict__ pt,
                         const float* __restrict__ ls,
                         unsigned short* __restrict__ xbf, unsigned short* __restrict__ pbf,
                         float* __restrict__ x2, float* __restrict__ fx,
                         float* __restrict__ gy, float* __restrict__ hy,
                         float* __restrict__ es2, int M, int N, int D) {
  int row = blockIdx.x * (blockDim.x >> 6) + (threadIdx.x >> 6);
  int lane = threadIdx.x & 63;
  if (row >= M + N) return;
  const bool isX = row < M;
  const int r = isX ? row : row - M;
  const float* src = (isX ? x : pt) + (size_t)r * D;
  f32x4 v = ((const f32x4*)src)[lane];
  float ss = v[0]*v[0] + v[1]*v[1] + v[2]*v[2] + v[3]*v[3];
  #pragma unroll
  for (int off = 32; off >= 1; off >>= 1) ss += __shfl_xor(ss, off);
  float scale = 1.0f;
  float outsq = ss;
  if (!isX) {
    float vn  = sqrtf(ss);
    float vnc = fmaxf(vn, 1e-15f);
    float th  = tanhf(vnc);
    scale = th / vnc;                 // p = scale * v
    float pn = scale * vn;            // ||p||
    if (pn > MAX_NORM) { float pr = MAX_NORM / pn; scale *= pr; pn = MAX_NORM; }
    outsq = pn * pn;
  }
  unsigned short* dst = (isX ? xbf : pbf) + (size_t)r * D + lane * 4;
  unsigned long long pk =
        (unsigned long long)f2bf(v[0]*scale)
      | ((unsigned long long)f2bf(v[1]*scale) << 16)
      | ((unsigned long long)f2bf(v[2]*scale) << 32)
      | ((unsigned long long)f2bf(v[3]*scale) << 48);
  *(unsigned long long*)dst = pk;
  if (lane == 0) {
    if (isX) {
      x2[r] = outsq;
      fx[r] = 2.0f / (1.0f - outsq);
    } else {
      float g = 1.0f / (1.0f - outsq);
      gy[r]  = g;
      hy[r]  = g * outsq;
      es2[r] = -__expf(ls[r]) * LN2;
    }
  }
}

// R11/R13 structure (best 53.0 us): 4 N-adjacent 128x128 sub-tiles per block,
// pipelined epilogue slices, BK=64 dbuf, __syncthreads, swapped-operand MFMA,
// plain f32x4 stores, setprio around MFMA. ONE change: PARITY-STAGGERED
// schedule. Co-resident blocks (bid, bid+256) run complementary per-iteration
// orders -- even: STAGE->EPI->COMPUTE, odd: STAGE->COMPUTE->EPI -- breaking
// the convoy lock where both blocks hit the same pipe (MFMA/trans/store)
// simultaneously. Order within an iteration is semantically free (EPI uses
// the previous sub-tile's acc); dispatch-order assumption affects speed only.
__global__ __launch_bounds__(256, 2)
void hyp_gemm(const unsigned short* __restrict__ xbf,
              const unsigned short* __restrict__ pbf,
              const float* __restrict__ x2, const float* __restrict__ fx,
              const float* __restrict__ gy, const float* __restrict__ hy,
              const float* __restrict__ es2, float* __restrict__ out,
              int M, int N, int K) {
  __shared__ __align__(16) unsigned short As[2][2][128 * 32];
  __shared__ __align__(16) unsigned short Bs[2][2][128 * 32];
  const int t    = threadIdx.x;
  const int wv   = t >> 6;
  const int lane = t & 63;
  const int wr   = wv >> 1, wc = wv & 1;
  const int frow = lane & 15, kgrp = lane >> 4;
  const int nTM  = M >> 7;
  const int tileM  = blockIdx.x % nTM;
  const int tileN0 = (blockIdx.x / nTM) * 4;    // four 128-wide N sub-tiles
  const int gr0 = tileM * 128 + wr * 64;
  const int ph  = (blockIdx.x >> 8) & 1;        // co-resident-pair parity

  f32x4 accA[4][4], accB[4][4];

  // staging: per plane (32 k-elems), per j (64-row half): wave wv covers rows
  // j*64 + wv*16 + (lane>>2), k-elems (lane&3)*8 .. +8  (16 B per lane)
  const int srow  = wv * 16 + (lane >> 2);
  const int skoff = (lane & 3) * 8;
  const unsigned short* gA  = xbf + (size_t)(tileM * 128 + srow) * K + skoff;
  const unsigned short* gB0 = pbf + (size_t)(tileN0 * 128 + srow) * K + skoff;
  const size_t rskip = (size_t)64 * K;    // 64-row half advance
  const size_t nskip = (size_t)128 * K;   // sub-tile (128-row) advance

  // epilogue per-M-row scalars, shared by all 4 sub-tiles
  float x2s[4], fxs[4];
  #pragma unroll
  for (int m = 0; m < 4; ++m) {
    x2s[m] = x2[gr0 + m * 16 + frow];
    fxs[m] = fx[gr0 + m * 16 + frow];
  }

#define STAGE(b, kt, GBP)                                                      \
  {                                                                            \
    _Pragma("unroll")                                                          \
    for (int p = 0; p < 2; ++p) {                                              \
      _Pragma("unroll")                                                        \
      for (int j = 0; j < 2; ++j) {                                            \
        gld16(gA + (size_t)j * rskip + (kt) * 64 + p * 32,                     \
              &As[b][p][(j * 64 + wv * 16) * 32]);                             \
        gld16((GBP) + (size_t)j * rskip + (kt) * 64 + p * 32,                  \
              &Bs[b][p][(j * 64 + wv * 16) * 32]);                             \
      }                                                                        \
    }                                                                          \
  }

#define COMPUTE(b, ACC)                                                        \
  {                                                                            \
    __builtin_amdgcn_s_setprio(1);                                             \
    _Pragma("unroll")                                                          \
    for (int p = 0; p < 2; ++p) {                                              \
      bf16x8 af[4], bg[4];                                                     \
      _Pragma("unroll")                                                        \
      for (int m = 0; m < 4; ++m)                                              \
        af[m] = *(const bf16x8*)&As[b][p][(wr * 64 + m * 16 + frow) * 32 + kgrp * 8]; \
      _Pragma("unroll")                                                        \
      for (int n = 0; n < 4; ++n)                                              \
        bg[n] = *(const bf16x8*)&Bs[b][p][(wc * 64 + n * 16 + frow) * 32 + kgrp * 8]; \
      _Pragma("unroll")                                                        \
      for (int m = 0; m < 4; ++m)                                              \
        _Pragma("unroll")                                                      \
        for (int n = 0; n < 4; ++n)                                            \
          ACC[m][n] = __builtin_amdgcn_mfma_f32_16x16x32_bf16(bg[n], af[m], ACC[m][n], 0, 0, 0); \
    }                                                                          \
    __builtin_amdgcn_s_setprio(0);                                             \
  }

  // one n-quarter of a finished sub-tile's epilogue (static NN = K-iter index)
  // u = 1 + fx*(gy*(x2-2xy) + hy); w = u + sqrt(u^2-1); out = es2*log2(w)
#define EPI_SLICE(ACC, TNP, NN)                                                \
  {                                                                            \
    const int c0 = (tileN0 + (TNP)) * 128 + wc * 64 + (NN) * 16 + kgrp * 4;    \
    f32x4 gv = *(const f32x4*)(gy  + c0);                                      \
    f32x4 hv = *(const f32x4*)(hy  + c0);                                      \
    f32x4 ev = *(const f32x4*)(es2 + c0);                                      \
    _Pragma("unroll")                                                          \
    for (int m = 0; m < 4; ++m) {                                              \
      f32x4 a4 = ACC[m][(NN)];                                                 \
      f32x4 o;                                                                 \
      _Pragma("unroll")                                                        \
      for (int r = 0; r < 4; ++r) {                                            \
        float xy = a4[r];                                                      \
        float u  = fmaf(fxs[m], fmaf(gv[r], fmaf(-2.0f, xy, x2s[m]), hv[r]), 1.0f); \
        float t2 = fmaxf(fmaf(u, u, -1.0f), 0.0f);                             \
        float w  = fminf(u + __builtin_amdgcn_sqrtf(t2), WMAX);                \
        o[r] = ev[r] * __log2f(w);                                             \
      }                                                                        \
      *(f32x4*)&out[(size_t)(gr0 + m * 16 + frow) * N + c0] = o;               \
    }                                                                          \
  }

  // Pipeline: tile TN's K-loop carries tile TN-1's epilogue slices; tile
  // TN+1's first buffer is staged during TN's last K-iter (no bubble).
  // Parity stagger: even blocks EPI-then-COMPUTE, odd COMPUTE-then-EPI.
#define TILE(TN, ACCC, ACCP)                                                   \
  {                                                                            \
    _Pragma("unroll")                                                          \
    for (int m = 0; m < 4; ++m)                                                \
      _Pragma("unroll")                                                        \
      for (int n = 0; n < 4; ++n) ACCC[m][n] = (f32x4){0.f, 0.f, 0.f, 0.f};    \
    __syncthreads();                                                           \
    _Pragma("unroll")                                                          \
    for (int kt = 0; kt < 4; ++kt) {                                           \
      if (kt < 3)          STAGE(cur ^ 1, kt + 1, gB0 + (TN) * nskip)          \
      else if ((TN) < 3)   STAGE(cur ^ 1, 0, gB0 + ((TN) + 1) * nskip)         \
      if (ph == 0) {                                                           \
        if ((TN) > 0)      EPI_SLICE(ACCP, (TN) - 1, kt)                       \
        COMPUTE(cur, ACCC)                                                     \
      } else {                                                                 \
        COMPUTE(cur, ACCC)                                                     \
        if ((TN) > 0)      EPI_SLICE(ACCP, (TN) - 1, kt)                       \
      }                                                                        \
      __syncthreads();                                                         \
      cur ^= 1;                                                                \
    }                                                                          \
  }

  STAGE(0, 0, gB0)
  int cur = 0;
  TILE(0, accA, accB)
  TILE(1, accB, accA)
  TILE(2, accA, accB)
  TILE(3, accB, accA)
  // drain: tile3's epilogue
  #pragma unroll
  for (int n = 0; n < 4; ++n) EPI_SLICE(accB, 3, n)

#undef TILE
#undef EPI_SLICE
#undef COMPUTE
#undef STAGE
}

extern "C" void kernel_launch(void* const* d_in, const int* in_sizes, int n_in,
                              void* d_out, int out_size, void* d_ws, size_t ws_size,
                              hipStream_t stream) {
  const float* x  = (const float*)d_in[0];
  const float* pt = (const float*)d_in[1];
  const float* ls = (const float*)d_in[2];
  const int Csz = in_sizes[2];
  const int D   = in_sizes[1] / Csz;   // 256
  const int Bsz = in_sizes[0] / D;     // 4096
  const int M = Bsz, N = Csz, K = D;
  float* outp = (float*)d_out;

  char* ws = (char*)d_ws;
  unsigned short* xbf = (unsigned short*)ws; ws += (size_t)M * K * 2;
  unsigned short* pbf = (unsigned short*)ws; ws += (size_t)N * K * 2;
  float* x2  = (float*)ws; ws += (size_t)M * 4;
  float* fx  = (float*)ws; ws += (size_t)M * 4;
  float* gy  = (float*)ws; ws += (size_t)N * 4;
  float* hy  = (float*)ws; ws += (size_t)N * 4;
  float* es2 = (float*)ws; ws += (size_t)N * 4;

  hipLaunchKernelGGL(prep_all, dim3((M + N + 3) / 4), dim3(256), 0, stream,
                     x, pt, ls, xbf, pbf, x2, fx, gy, hy, es2, M, N, K);
  hipLaunchKernelGGL(hyp_gemm, dim3((M / 128) * (N / 512)), dim3(256), 0, stream,
                     xbf, pbf, x2, fx, gy, hy, es2, outp, M, N, K);
}

// Round 15
// 52.715 us; speedup vs baseline: 1.1860x; 1.1860x over previous
//
#include <hip/hip_runtime.h>
#include <hip/hip_bf16.h>
#include <cstdint>

#define MAX_NORM (1.0f - 1e-5f)
#define LN2 0.69314718056f
// w-clamp equivalent of norm <= MAX_NORM: w_max = (1+MAX_NORM)/(1-MAX_NORM)
#define WMAX ((1.0f + MAX_NORM) / (1.0f - MAX_NORM))

typedef __attribute__((ext_vector_type(8))) short bf16x8;
typedef __attribute__((ext_vector_type(4))) float f32x4;

__device__ __forceinline__ unsigned short f2bf(float f) {
  union { float f; unsigned int u; } c; c.f = f;
  unsigned int r = c.u + 0x7fffu + ((c.u >> 16) & 1u);
  return (unsigned short)(r >> 16);
}

__device__ __forceinline__ void gld16(const unsigned short* g, unsigned short* l) {
  __builtin_amdgcn_global_load_lds(
      (const __attribute__((address_space(1))) unsigned int*)g,
      (__attribute__((address_space(3))) unsigned int*)l, 16, 0, 0);
}

// Fused prep: one wave per row, rows [0,M) are x, rows [M,M+N) are protos.
// x:      bf16-cast; x2 = ||x||^2; fx = 2/(1-x2)
// protos: expmap0+project -> bf16; gy = 1/(1-y2); hy = gy*y2; es2 = -exp(ls)*ln2
__global__ void prep_all(const float* __restrict__ x, const float* __restrict__ pt,
                         const float* __restrict__ ls,
                         unsigned short* __restrict__ xbf, unsigned short* __restrict__ pbf,
                         float* __restrict__ x2, float* __restrict__ fx,
                         float* __restrict__ gy, float* __restrict__ hy,
                         float* __restrict__ es2, int M, int N, int D) {
  int row = blockIdx.x * (blockDim.x >> 6) + (threadIdx.x >> 6);
  int lane = threadIdx.x & 63;
  if (row >= M + N) return;
  const bool isX = row < M;
  const int r = isX ? row : row - M;
  const float* src = (isX ? x : pt) + (size_t)r * D;
  f32x4 v = ((const f32x4*)src)[lane];
  float ss = v[0]*v[0] + v[1]*v[1] + v[2]*v[2] + v[3]*v[3];
  #pragma unroll
  for (int off = 32; off >= 1; off >>= 1) ss += __shfl_xor(ss, off);
  float scale = 1.0f;
  float outsq = ss;
  if (!isX) {
    float vn  = sqrtf(ss);
    float vnc = fmaxf(vn, 1e-15f);
    float th  = tanhf(vnc);
    scale = th / vnc;                 // p = scale * v
    float pn = scale * vn;            // ||p||
    if (pn > MAX_NORM) { float pr = MAX_NORM / pn; scale *= pr; pn = MAX_NORM; }
    outsq = pn * pn;
  }
  unsigned short* dst = (isX ? xbf : pbf) + (size_t)r * D + lane * 4;
  unsigned long long pk =
        (unsigned long long)f2bf(v[0]*scale)
      | ((unsigned long long)f2bf(v[1]*scale) << 16)
      | ((unsigned long long)f2bf(v[2]*scale) << 32)
      | ((unsigned long long)f2bf(v[3]*scale) << 48);
  *(unsigned long long*)dst = pk;
  if (lane == 0) {
    if (isX) {
      x2[r] = outsq;
      fx[r] = 2.0f / (1.0f - outsq);
    } else {
      float g = 1.0f / (1.0f - outsq);
      gy[r]  = g;
      hy[r]  = g * outsq;
      es2[r] = -__expf(ls[r]) * LN2;
    }
  }
}

// R13 structure (best 53.0 us): 4 N-adjacent 128x128 sub-tiles per block,
// pipelined epilogue, BK=64 dbuf, __syncthreads, swapped-operand MFMA,
// setprio around MFMA. ONE change: PAIRED-NN epilogue slices -> each wave
// writes 128 B-ALIGNED, 128 B-CONTIGUOUS row segments (two adjacent f32x4
// stores back-to-back) instead of isolated 64 B half-lines whose partner
// arrived a whole K-iteration later. Full lines reach L2 immediately -> no
// read-modify-write exposure on the 134 MB output stream.
__global__ __launch_bounds__(256, 2)
void hyp_gemm(const unsigned short* __restrict__ xbf,
              const unsigned short* __restrict__ pbf,
              const float* __restrict__ x2, const float* __restrict__ fx,
              const float* __restrict__ gy, const float* __restrict__ hy,
              const float* __restrict__ es2, float* __restrict__ out,
              int M, int N, int K) {
  __shared__ __align__(16) unsigned short As[2][2][128 * 32];
  __shared__ __align__(16) unsigned short Bs[2][2][128 * 32];
  const int t    = threadIdx.x;
  const int wv   = t >> 6;
  const int lane = t & 63;
  const int wr   = wv >> 1, wc = wv & 1;
  const int frow = lane & 15, kgrp = lane >> 4;
  const int nTM  = M >> 7;
  const int tileM  = blockIdx.x % nTM;
  const int tileN0 = (blockIdx.x / nTM) * 4;    // four 128-wide N sub-tiles
  const int gr0 = tileM * 128 + wr * 64;

  f32x4 accA[4][4], accB[4][4];

  // staging: per plane (32 k-elems), per j (64-row half): wave wv covers rows
  // j*64 + wv*16 + (lane>>2), k-elems (lane&3)*8 .. +8  (16 B per lane)
  const int srow  = wv * 16 + (lane >> 2);
  const int skoff = (lane & 3) * 8;
  const unsigned short* gA  = xbf + (size_t)(tileM * 128 + srow) * K + skoff;
  const unsigned short* gB0 = pbf + (size_t)(tileN0 * 128 + srow) * K + skoff;
  const size_t rskip = (size_t)64 * K;    // 64-row half advance
  const size_t nskip = (size_t)128 * K;   // sub-tile (128-row) advance

  // epilogue per-M-row scalars, shared by all 4 sub-tiles
  float x2s[4], fxs[4];
  #pragma unroll
  for (int m = 0; m < 4; ++m) {
    x2s[m] = x2[gr0 + m * 16 + frow];
    fxs[m] = fx[gr0 + m * 16 + frow];
  }

#define STAGE(b, kt, GBP)                                                      \
  {                                                                            \
    _Pragma("unroll")                                                          \
    for (int p = 0; p < 2; ++p) {                                              \
      _Pragma("unroll")                                                        \
      for (int j = 0; j < 2; ++j) {                                            \
        gld16(gA + (size_t)j * rskip + (kt) * 64 + p * 32,                     \
              &As[b][p][(j * 64 + wv * 16) * 32]);                             \
        gld16((GBP) + (size_t)j * rskip + (kt) * 64 + p * 32,                  \
              &Bs[b][p][(j * 64 + wv * 16) * 32]);                             \
      }                                                                        \
    }                                                                          \
  }

#define COMPUTE(b, ACC)                                                        \
  {                                                                            \
    __builtin_amdgcn_s_setprio(1);                                             \
    _Pragma("unroll")                                                          \
    for (int p = 0; p < 2; ++p) {                                              \
      bf16x8 af[4], bg[4];                                                     \
      _Pragma("unroll")                                                        \
      for (int m = 0; m < 4; ++m)                                              \
        af[m] = *(const bf16x8*)&As[b][p][(wr * 64 + m * 16 + frow) * 32 + kgrp * 8]; \
      _Pragma("unroll")                                                        \
      for (int n = 0; n < 4; ++n)                                              \
        bg[n] = *(const bf16x8*)&Bs[b][p][(wc * 64 + n * 16 + frow) * 32 + kgrp * 8]; \
      _Pragma("unroll")                                                        \
      for (int m = 0; m < 4; ++m)                                              \
        _Pragma("unroll")                                                      \
        for (int n = 0; n < 4; ++n)                                            \
          ACC[m][n] = __builtin_amdgcn_mfma_f32_16x16x32_bf16(bg[n], af[m], ACC[m][n], 0, 0, 0); \
    }                                                                          \
    __builtin_amdgcn_s_setprio(0);                                             \
  }

  // paired epilogue slice: NN = 2*NNP and 2*NNP+1 together. Per row the wave
  // writes cols [base+NNP*32, base+NNP*32+32) = one ALIGNED 128 B line via
  // two adjacent f32x4 stores (no half-line RMW exposure).
  // u = 1 + fx*(gy*(x2-2xy) + hy); w = u + sqrt(u^2-1); out = es2*log2(w)
#define EPI_PAIR(ACC, TNP, NNP)                                                \
  {                                                                            \
    const int c0 = (tileN0 + (TNP)) * 128 + wc * 64 + (NNP) * 32 + kgrp * 4;   \
    f32x4 gv0 = *(const f32x4*)(gy  + c0);                                     \
    f32x4 hv0 = *(const f32x4*)(hy  + c0);                                     \
    f32x4 ev0 = *(const f32x4*)(es2 + c0);                                     \
    f32x4 gv1 = *(const f32x4*)(gy  + c0 + 16);                                \
    f32x4 hv1 = *(const f32x4*)(hy  + c0 + 16);                                \
    f32x4 ev1 = *(const f32x4*)(es2 + c0 + 16);                                \
    _Pragma("unroll")                                                          \
    for (int m = 0; m < 4; ++m) {                                              \
      f32x4 a0 = ACC[m][2 * (NNP)];                                            \
      f32x4 a1 = ACC[m][2 * (NNP) + 1];                                        \
      f32x4 o0, o1;                                                            \
      _Pragma("unroll")                                                        \
      for (int r = 0; r < 4; ++r) {                                            \
        float u0  = fmaf(fxs[m], fmaf(gv0[r], fmaf(-2.0f, a0[r], x2s[m]), hv0[r]), 1.0f); \
        float t20 = fmaxf(fmaf(u0, u0, -1.0f), 0.0f);                          \
        float w0  = fminf(u0 + __builtin_amdgcn_sqrtf(t20), WMAX);             \
        o0[r] = ev0[r] * __log2f(w0);                                          \
        float u1  = fmaf(fxs[m], fmaf(gv1[r], fmaf(-2.0f, a1[r], x2s[m]), hv1[r]), 1.0f); \
        float t21 = fmaxf(fmaf(u1, u1, -1.0f), 0.0f);                          \
        float w1  = fminf(u1 + __builtin_amdgcn_sqrtf(t21), WMAX);             \
        o1[r] = ev1[r] * __log2f(w1);                                          \
      }                                                                        \
      float* po = &out[(size_t)(gr0 + m * 16 + frow) * N + c0];                \
      *(f32x4*)po        = o0;                                                 \
      *(f32x4*)(po + 16) = o1;                                                 \
    }                                                                          \
  }

  // Pipeline: tile TN's K-loop carries tile TN-1's epilogue in 2 paired
  // slices (kt=1 and kt=3); tile TN+1's first buffer staged at kt=3.
#define TILE(TN, ACCC, ACCP)                                                   \
  {                                                                            \
    _Pragma("unroll")                                                          \
    for (int m = 0; m < 4; ++m)                                                \
      _Pragma("unroll")                                                        \
      for (int n = 0; n < 4; ++n) ACCC[m][n] = (f32x4){0.f, 0.f, 0.f, 0.f};    \
    __syncthreads();                                                           \
    _Pragma("unroll")                                                          \
    for (int kt = 0; kt < 4; ++kt) {                                           \
      if (kt < 3)          STAGE(cur ^ 1, kt + 1, gB0 + (TN) * nskip)          \
      else if ((TN) < 3)   STAGE(cur ^ 1, 0, gB0 + ((TN) + 1) * nskip)         \
      if ((TN) > 0 && kt == 1) EPI_PAIR(ACCP, (TN) - 1, 0)                     \
      if ((TN) > 0 && kt == 3) EPI_PAIR(ACCP, (TN) - 1, 1)                     \
      COMPUTE(cur, ACCC)                                                       \
      __syncthreads();                                                         \
      cur ^= 1;                                                                \
    }                                                                          \
  }

  STAGE(0, 0, gB0)
  int cur = 0;
  TILE(0, accA, accB)
  TILE(1, accB, accA)
  TILE(2, accA, accB)
  TILE(3, accB, accA)
  // drain: tile3's epilogue
  EPI_PAIR(accB, 3, 0)
  EPI_PAIR(accB, 3, 1)

#undef TILE
#undef EPI_PAIR
#undef COMPUTE
#undef STAGE
}

extern "C" void kernel_launch(void* const* d_in, const int* in_sizes, int n_in,
                              void* d_out, int out_size, void* d_ws, size_t ws_size,
                              hipStream_t stream) {
  const float* x  = (const float*)d_in[0];
  const float* pt = (const float*)d_in[1];
  const float* ls = (const float*)d_in[2];
  const int Csz = in_sizes[2];
  const int D   = in_sizes[1] / Csz;   // 256
  const int Bsz = in_sizes[0] / D;     // 4096
  const int M = Bsz, N = Csz, K = D;
  float* outp = (float*)d_out;

  char* ws = (char*)d_ws;
  unsigned short* xbf = (unsigned short*)ws; ws += (size_t)M * K * 2;
  unsigned short* pbf = (unsigned short*)ws; ws += (size_t)N * K * 2;
  float* x2  = (float*)ws; ws += (size_t)M * 4;
  float* fx  = (float*)ws; ws += (size_t)M * 4;
  float* gy  = (float*)ws; ws += (size_t)N * 4;
  float* hy  = (float*)ws; ws += (size_t)N * 4;
  float* es2 = (float*)ws; ws += (size_t)N * 4;

  hipLaunchKernelGGL(prep_all, dim3((M + N + 3) / 4), dim3(256), 0, stream,
                     x, pt, ls, xbf, pbf, x2, fx, gy, hy, es2, M, N, K);
  hipLaunchKernelGGL(hyp_gemm, dim3((M / 128) * (N / 512)), dim3(256), 0, stream,
                     xbf, pbf, x2, fx, gy, hy, es2, outp, M, N, K);
}

// Round 16
// 51.773 us; speedup vs baseline: 1.2076x; 1.0182x over previous
//
#include <hip/hip_runtime.h>
#include <hip/hip_bf16.h>
#include <cstdint>

#define MAX_NORM (1.0f - 1e-5f)
#define LN2 0.69314718056f
// w-clamp equivalent of norm <= MAX_NORM: w_max = (1+MAX_NORM)/(1-MAX_NORM)
#define WMAX ((1.0f + MAX_NORM) / (1.0f - MAX_NORM))

typedef __attribute__((ext_vector_type(8))) short bf16x8;
typedef __attribute__((ext_vector_type(4))) float f32x4;

__device__ __forceinline__ unsigned short f2bf(float f) {
  union { float f; unsigned int u; } c; c.f = f;
  unsigned int r = c.u + 0x7fffu + ((c.u >> 16) & 1u);
  return (unsigned short)(r >> 16);
}

__device__ __forceinline__ void gld16(const unsigned short* g, unsigned short* l) {
  __builtin_amdgcn_global_load_lds(
      (const __attribute__((address_space(1))) unsigned int*)g,
      (__attribute__((address_space(3))) unsigned int*)l, 16, 0, 0);
}

#define WVM0 asm volatile("s_waitcnt vmcnt(0)" ::: "memory")
#define WVM3 asm volatile("s_waitcnt vmcnt(3)" ::: "memory")

// Fused prep: one wave per row, rows [0,M) are x, rows [M,M+N) are protos.
// x:      bf16-cast; x2 = ||x||^2; fx = 2/(1-x2)
// protos: expmap0+project -> bf16; gy = 1/(1-y2); hy = gy*y2; es2 = -exp(ls)*ln2
__global__ void prep_all(const float* __restrict__ x, const float* __restrict__ pt,
                         const float* __restrict__ ls,
                         unsigned short* __restrict__ xbf, unsigned short* __restrict__ pbf,
                         float* __restrict__ x2, float* __restrict__ fx,
                         float* __restrict__ gy, float* __restrict__ hy,
                         float* __restrict__ es2, int M, int N, int D) {
  int row = blockIdx.x * (blockDim.x >> 6) + (threadIdx.x >> 6);
  int lane = threadIdx.x & 63;
  if (row >= M + N) return;
  const bool isX = row < M;
  const int r = isX ? row : row - M;
  const float* src = (isX ? x : pt) + (size_t)r * D;
  f32x4 v = ((const f32x4*)src)[lane];
  float ss = v[0]*v[0] + v[1]*v[1] + v[2]*v[2] + v[3]*v[3];
  #pragma unroll
  for (int off = 32; off >= 1; off >>= 1) ss += __shfl_xor(ss, off);
  float scale = 1.0f;
  float outsq = ss;
  if (!isX) {
    float vn  = sqrtf(ss);
    float vnc = fmaxf(vn, 1e-15f);
    float th  = tanhf(vnc);
    scale = th / vnc;                 // p = scale * v
    float pn = scale * vn;            // ||p||
    if (pn > MAX_NORM) { float pr = MAX_NORM / pn; scale *= pr; pn = MAX_NORM; }
    outsq = pn * pn;
  }
  unsigned short* dst = (isX ? xbf : pbf) + (size_t)r * D + lane * 4;
  unsigned long long pk =
        (unsigned long long)f2bf(v[0]*scale)
      | ((unsigned long long)f2bf(v[1]*scale) << 16)
      | ((unsigned long long)f2bf(v[2]*scale) << 32)
      | ((unsigned long long)f2bf(v[3]*scale) << 48);
  *(unsigned long long*)dst = pk;
  if (lane == 0) {
    if (isX) {
      x2[r] = outsq;
      fx[r] = 2.0f / (1.0f - outsq);
    } else {
      float g = 1.0f / (1.0f - outsq);
      gy[r]  = g;
      hy[r]  = g * outsq;
      es2[r] = -__expf(ls[r]) * LN2;
    }
  }
}

// R13/R15 structure (4 N-adjacent 128x128 sub-tiles/block, pipelined epilogue,
// BK=64 dbuf, swapped-operand MFMA, setprio) with SINGLE-BARRIER COUNTED-VMCNT
// loop: per iter {vmcnt(3|0); s_barrier; EPI_STORE(prev slice); COMPUTE;
// STAGE(next); EPI_LOAD(next slice)}. Queue order [stores4, stage8, tbl3]
// means vmcnt(3) drains stores+staging exactly, leaving next-EPI table loads
// in flight; EPI tables pipelined one iter ahead so no wait ever drains the
// prefetch. Barriers 20->16, no vmcnt(0) full drains in steady state.
__global__ __launch_bounds__(256, 2)
void hyp_gemm(const unsigned short* __restrict__ xbf,
              const unsigned short* __restrict__ pbf,
              const float* __restrict__ x2, const float* __restrict__ fx,
              const float* __restrict__ gy, const float* __restrict__ hy,
              const float* __restrict__ es2, float* __restrict__ out,
              int M, int N, int K) {
  __shared__ __align__(16) unsigned short As[2][2][128 * 32];
  __shared__ __align__(16) unsigned short Bs[2][2][128 * 32];
  const int t    = threadIdx.x;
  const int wv   = t >> 6;
  const int lane = t & 63;
  const int wr   = wv >> 1, wc = wv & 1;
  const int frow = lane & 15, kgrp = lane >> 4;
  const int nTM  = M >> 7;
  const int tileM  = blockIdx.x % nTM;
  const int tileN0 = (blockIdx.x / nTM) * 4;    // four 128-wide N sub-tiles
  const int gr0 = tileM * 128 + wr * 64;

  f32x4 accA[4][4], accB[4][4];
  f32x4 e_gv, e_hv, e_ev;   // EPI tables, pipelined one iteration ahead

  // staging: per plane (32 k-elems), per j (64-row half): wave wv covers rows
  // j*64 + wv*16 + (lane>>2), k-elems (lane&3)*8 .. +8  (16 B per lane)
  const int srow  = wv * 16 + (lane >> 2);
  const int skoff = (lane & 3) * 8;
  const unsigned short* gA  = xbf + (size_t)(tileM * 128 + srow) * K + skoff;
  const unsigned short* gB0 = pbf + (size_t)(tileN0 * 128 + srow) * K + skoff;
  const size_t rskip = (size_t)64 * K;    // 64-row half advance
  const size_t nskip = (size_t)128 * K;   // sub-tile (128-row) advance

  // epilogue per-M-row scalars, shared by all 4 sub-tiles
  float x2s[4], fxs[4];
  #pragma unroll
  for (int m = 0; m < 4; ++m) {
    x2s[m] = x2[gr0 + m * 16 + frow];
    fxs[m] = fx[gr0 + m * 16 + frow];
  }

#define STAGE(b, kt, GBP)                                                      \
  {                                                                            \
    _Pragma("unroll")                                                          \
    for (int p = 0; p < 2; ++p) {                                              \
      _Pragma("unroll")                                                        \
      for (int j = 0; j < 2; ++j) {                                            \
        gld16(gA + (size_t)j * rskip + (kt) * 64 + p * 32,                     \
              &As[b][p][(j * 64 + wv * 16) * 32]);                             \
        gld16((GBP) + (size_t)j * rskip + (kt) * 64 + p * 32,                  \
              &Bs[b][p][(j * 64 + wv * 16) * 32]);                             \
      }                                                                        \
    }                                                                          \
  }

#define COMPUTE(b, ACC)                                                        \
  {                                                                            \
    __builtin_amdgcn_s_setprio(1);                                             \
    _Pragma("unroll")                                                          \
    for (int p = 0; p < 2; ++p) {                                              \
      bf16x8 af[4], bg[4];                                                     \
      _Pragma("unroll")                                                        \
      for (int m = 0; m < 4; ++m)                                              \
        af[m] = *(const bf16x8*)&As[b][p][(wr * 64 + m * 16 + frow) * 32 + kgrp * 8]; \
      _Pragma("unroll")                                                        \
      for (int n = 0; n < 4; ++n)                                              \
        bg[n] = *(const bf16x8*)&Bs[b][p][(wc * 64 + n * 16 + frow) * 32 + kgrp * 8]; \
      _Pragma("unroll")                                                        \
      for (int m = 0; m < 4; ++m)                                              \
        _Pragma("unroll")                                                      \
        for (int n = 0; n < 4; ++n)                                            \
          ACC[m][n] = __builtin_amdgcn_mfma_f32_16x16x32_bf16(bg[n], af[m], ACC[m][n], 0, 0, 0); \
    }                                                                          \
    __builtin_amdgcn_s_setprio(0);                                             \
  }

  // load tables for slice (TNP, NN) into e_gv/e_hv/e_ev (consumed next iter)
#define EPI_LOAD(TNP, NN)                                                      \
  {                                                                            \
    const int c0 = (tileN0 + (TNP)) * 128 + wc * 64 + (NN) * 16 + kgrp * 4;    \
    e_gv = *(const f32x4*)(gy  + c0);                                          \
    e_hv = *(const f32x4*)(hy  + c0);                                          \
    e_ev = *(const f32x4*)(es2 + c0);                                          \
  }

  // u = 1 + fx*(gy*(x2-2xy) + hy); w = u + sqrt(u^2-1); out = es2*log2(w)
#define EPI_STORE(ACC, TNP, NN)                                                \
  {                                                                            \
    const int c0 = (tileN0 + (TNP)) * 128 + wc * 64 + (NN) * 16 + kgrp * 4;    \
    _Pragma("unroll")                                                          \
    for (int m = 0; m < 4; ++m) {                                              \
      f32x4 a4 = ACC[m][(NN)];                                                 \
      f32x4 o;                                                                 \
      _Pragma("unroll")                                                        \
      for (int r = 0; r < 4; ++r) {                                            \
        float u  = fmaf(fxs[m], fmaf(e_gv[r], fmaf(-2.0f, a4[r], x2s[m]), e_hv[r]), 1.0f); \
        float t2 = fmaxf(fmaf(u, u, -1.0f), 0.0f);                             \
        float w  = fminf(u + __builtin_amdgcn_sqrtf(t2), WMAX);                \
        o[r] = e_ev[r] * __log2f(w);                                           \
      }                                                                        \
      *(f32x4*)&out[(size_t)(gr0 + m * 16 + frow) * N + c0] = o;               \
    }                                                                          \
  }

  // Per iter: {wait; barrier; EPI_STORE(prev, tbl in regs); COMPUTE;
  // STAGE(next); EPI_LOAD(next slice)}. Wait = vmcnt(3) when a next-slice
  // table load is in flight (TN>0), else vmcnt(0).
#define TILE(TN, ACCC, ACCP)                                                   \
  {                                                                            \
    _Pragma("unroll")                                                          \
    for (int m = 0; m < 4; ++m)                                                \
      _Pragma("unroll")                                                        \
      for (int n = 0; n < 4; ++n) ACCC[m][n] = (f32x4){0.f, 0.f, 0.f, 0.f};    \
    _Pragma("unroll")                                                          \
    for (int kt = 0; kt < 4; ++kt) {                                           \
      if ((TN) > 0) { WVM3; } else { WVM0; }                                   \
      __builtin_amdgcn_s_barrier();                                            \
      if ((TN) > 0) EPI_STORE(ACCP, (TN) - 1, kt)                              \
      COMPUTE(cur, ACCC)                                                       \
      if (kt < 3)        STAGE(cur ^ 1, kt + 1, gB0 + (TN) * nskip)            \
      else if ((TN) < 3) STAGE(cur ^ 1, 0, gB0 + ((TN) + 1) * nskip)           \
      if (kt < 3) { if ((TN) > 0) EPI_LOAD((TN) - 1, kt + 1) }                 \
      else          EPI_LOAD((TN), 0)                                          \
      cur ^= 1;                                                                \
    }                                                                          \
  }

  STAGE(0, 0, gB0)
  int cur = 0;
  TILE(0, accA, accB)
  TILE(1, accB, accA)
  TILE(2, accA, accB)
  TILE(3, accB, accA)
  // drain: tile3's epilogue (tables for (3,0) already in regs from (3,3))
  EPI_STORE(accB, 3, 0) EPI_LOAD(3, 1)
  EPI_STORE(accB, 3, 1) EPI_LOAD(3, 2)
  EPI_STORE(accB, 3, 2) EPI_LOAD(3, 3)
  EPI_STORE(accB, 3, 3)

#undef TILE
#undef EPI_LOAD
#undef EPI_STORE
#undef COMPUTE
#undef STAGE
}

extern "C" void kernel_launch(void* const* d_in, const int* in_sizes, int n_in,
                              void* d_out, int out_size, void* d_ws, size_t ws_size,
                              hipStream_t stream) {
  const float* x  = (const float*)d_in[0];
  const float* pt = (const float*)d_in[1];
  const float* ls = (const float*)d_in[2];
  const int Csz = in_sizes[2];
  const int D   = in_sizes[1] / Csz;   // 256
  const int Bsz = in_sizes[0] / D;     // 4096
  const int M = Bsz, N = Csz, K = D;
  float* outp = (float*)d_out;

  char* ws = (char*)d_ws;
  unsigned short* xbf = (unsigned short*)ws; ws += (size_t)M * K * 2;
  unsigned short* pbf = (unsigned short*)ws; ws += (size_t)N * K * 2;
  float* x2  = (float*)ws; ws += (size_t)M * 4;
  float* fx  = (float*)ws; ws += (size_t)M * 4;
  float* gy  = (float*)ws; ws += (size_t)N * 4;
  float* hy  = (float*)ws; ws += (size_t)N * 4;
  float* es2 = (float*)ws; ws += (size_t)N * 4;

  hipLaunchKernelGGL(prep_all, dim3((M + N + 3) / 4), dim3(256), 0, stream,
                     x, pt, ls, xbf, pbf, x2, fx, gy, hy, es2, M, N, K);
  hipLaunchKernelGGL(hyp_gemm, dim3((M / 128) * (N / 512)), dim3(256), 0, stream,
                     xbf, pbf, x2, fx, gy, hy, es2, outp, M, N, K);
}